// Round 9
// baseline (188.339 us; speedup 1.0000x reference)
//
#include <hip/hip_runtime.h>

#define AS1 __attribute__((address_space(1)))
#define AS3 __attribute__((address_space(3)))

using f32x4 = __attribute__((ext_vector_type(4))) float;
using s16x8 = __attribute__((ext_vector_type(8))) short;
using u16x4 = __attribute__((ext_vector_type(4))) unsigned short;
using u32x2 = __attribute__((ext_vector_type(2))) unsigned int;

__device__ __forceinline__ unsigned short f2bf(float f) {
  union { float f; unsigned u; } v; v.f = f;
  unsigned u = v.u;
  return (unsigned short)((u + 0x7FFFu + ((u >> 16) & 1u)) >> 16);  // RNE
}

__device__ __forceinline__ unsigned pack_bf2(float a, float b) {  // trunc; P in [0,1]
  union { float f; unsigned u; } x, y; x.f = a; y.f = b;
  return (x.u >> 16) | (y.u & 0xFFFF0000u);
}

__device__ __forceinline__ void load_lds16(const void* g, void* l) {
  __builtin_amdgcn_global_load_lds((const AS1 void*)g, (AS3 void*)l, 16, 0, 0);
}

// Work LUT: 48 items per head = 16 unsplit q-tiles (t=0..15) + 16 split tiles
// (t=16..31, two j-halves). Arranged as 8 columns x 6 rows, each column sums to
// exactly 66 j-iters -> the 6 blocks resident on one CU have equal total work.
__constant__ unsigned char LUT_T[48] = {
  15,30,31, 8, 7, 0,   31,14,13, 9,16, 1,   28,29,12,10,17, 2,   29,26,24,11,16, 3,
  30,27,25,22, 6, 4,   27,25,23,20,18, 5,   28,23,21,19,19,17,   26,24,21,22,20,18};
__constant__ unsigned char LUT_JB[48] = {
   0, 0, 0, 0, 0, 0,   16, 0, 0, 0, 0, 0,    0, 0, 0, 0, 0, 0,   15, 0, 0, 0, 9, 0,
  16, 0, 0, 0, 0, 0,   14,13, 0, 0, 0, 0,   15,12, 0, 0,10, 9,   14,13,11,12,11,10};
__constant__ unsigned char LUT_JE[48] = {
  16,16,16, 9, 8, 1,   32,15,14,10, 9, 2,   15,15,13,11, 9, 3,   30,14,13,12,17, 4,
  31,14,13,12, 7, 5,   28,26,12,11,10, 6,   29,24,11,10,20,18,   27,25,22,23,21,19};

// ---------------- fused prep: cast x + transpose both weights ----------------
__global__ __launch_bounds__(256) void prep_kernel(const float* __restrict__ x,
                                                   const float* __restrict__ w_qkv,
                                                   const float* __restrict__ w_proj,
                                                   unsigned short* __restrict__ xb,
                                                   unsigned short* __restrict__ wqkvT,
                                                   unsigned short* __restrict__ wprojT) {
  __shared__ float tile[32][33];
  const int bid = blockIdx.x, tid = threadIdx.x;
  if (bid < 4096) {
    int i = bid * 256 + tid;
    float4 v = ((const float4*)x)[i];
    u16x4 o;
    o.x = f2bf(v.x); o.y = f2bf(v.y); o.z = f2bf(v.z); o.w = f2bf(v.w);
    ((u16x4*)xb)[i] = o;
    return;
  }
  const float* in;
  unsigned short* out;
  int bx, by, R, C;
  if (bid < 7168) {
    int t = bid - 4096;
    bx = t % 96; by = t / 96; R = 1024; C = 3072;
    in = w_qkv; out = wqkvT;
  } else {
    int t = bid - 7168;
    bx = t % 32; by = t / 32; R = 1024; C = 1024;
    in = w_proj; out = wprojT;
  }
  const int tx = tid & 31, ty = tid >> 5;
  int xcol = bx * 32 + tx;
  int y0 = by * 32;
  for (int j = ty; j < 32; j += 8)
    tile[j][tx] = in[(size_t)(y0 + j) * C + xcol];
  __syncthreads();
  int x2 = by * 32 + tx;
  int y2 = bx * 32;
  for (int j = ty; j < 32; j += 8)
    out[(size_t)(y2 + j) * R + x2] = f2bf(tile[tx][j]);
}

// ---------------- V transpose: qkv V block [s][d] -> Vt[b][h][d][s] ----------------
__global__ __launch_bounds__(256) void transpose_v(const unsigned short* __restrict__ qkv,
                                                   unsigned short* __restrict__ Vt) {
  __shared__ unsigned short tile[64][65];
  const int tid = threadIdx.x;
  const int bh = blockIdx.y, b = bh >> 4, h = bh & 15;
  const int s0 = blockIdx.x * 64;
#pragma unroll
  for (int it = 0; it < 2; ++it) {
    int c = tid + it * 256;
    int row = c >> 3, cc = c & 7;
    s16x8 v = *(const s16x8*)(qkv + (size_t)(b * 2048 + s0 + row) * 3072 + 2048 + h * 64 + cc * 8);
#pragma unroll
    for (int j = 0; j < 8; ++j) tile[row][cc * 8 + j] = (unsigned short)v[j];
  }
  __syncthreads();
#pragma unroll
  for (int it = 0; it < 2; ++it) {
    int c = tid + it * 256;
    int d = c >> 3, sc = c & 7;
    s16x8 o;
#pragma unroll
    for (int j = 0; j < 8; ++j) o[j] = (short)tile[sc * 8 + j][d];
    *(s16x8*)(Vt + (size_t)bh * 64 * 2048 + (size_t)d * 2048 + s0 + sc * 8) = o;
  }
}

// ---------------- QKV GEMM: BK=64, XOR-swizzled LDS ----------------
__global__ __launch_bounds__(256) void gemm_qkv(const unsigned short* __restrict__ A,
                                                const unsigned short* __restrict__ Bt,
                                                unsigned short* __restrict__ C,
                                                int M, int N, int K) {
  __shared__ unsigned short As[128 * 64];
  __shared__ unsigned short Bs[128 * 64];
  const int tid = threadIdx.x;
  const int wave = tid >> 6, lane = tid & 63;
  const int l15 = lane & 15, quad = lane >> 4;
  const int sx = l15 & 7;
  const int wm = wave & 1, wn = wave >> 1;
  const int bm = blockIdx.y, bn = blockIdx.x;

  f32x4 acc[4][4] = {};

  for (int k0 = 0; k0 < K; k0 += 64) {
    __syncthreads();
#pragma unroll
    for (int s = 0; s < 4; ++s) {
      int c = tid + s * 256;
      int row = c >> 3, cc = c & 7;
      int kc = (cc ^ (row & 7)) * 8;
      load_lds16(A + (size_t)(bm * 128 + row) * K + k0 + kc, As + c * 8);
      load_lds16(Bt + (size_t)(bn * 128 + row) * K + k0 + kc, Bs + c * 8);
    }
    __syncthreads();
#pragma unroll
    for (int kk = 0; kk < 2; ++kk) {
      s16x8 af[4], bfr[4];
#pragma unroll
      for (int i = 0; i < 4; ++i) {
        af[i]  = *(const s16x8*)(As + (wm * 64 + i * 16 + l15) * 64 + ((quad + 4 * kk) ^ sx) * 8);
        bfr[i] = *(const s16x8*)(Bs + (wn * 64 + i * 16 + l15) * 64 + ((quad + 4 * kk) ^ sx) * 8);
      }
#pragma unroll
      for (int i = 0; i < 4; ++i)
#pragma unroll
        for (int j = 0; j < 4; ++j)
          acc[i][j] = __builtin_amdgcn_mfma_f32_16x16x32_bf16(af[i], bfr[j], acc[i][j], 0, 0, 0);
    }
  }

  const int row0 = bm * 128 + wm * 64 + quad * 4;
  const int col0 = bn * 128 + wn * 64 + l15;
#pragma unroll
  for (int i = 0; i < 4; ++i)
#pragma unroll
    for (int j = 0; j < 4; ++j)
#pragma unroll
      for (int r = 0; r < 4; ++r)
        C[(size_t)(row0 + i * 16 + r) * N + (col0 + j * 16)] = f2bf(acc[i][j][r]);
}

// ---------------- proj GEMM: 128Mx64N, BK=64, swizzled; f32 out ----------------
__global__ __launch_bounds__(256) void gemm_proj(const unsigned short* __restrict__ A,
                                                 const unsigned short* __restrict__ Bt,
                                                 float* __restrict__ C,
                                                 int M, int N, int K) {
  __shared__ unsigned short As[128 * 64];
  __shared__ unsigned short Bs[64 * 64];
  const int tid = threadIdx.x;
  const int wave = tid >> 6, lane = tid & 63;
  const int l15 = lane & 15, quad = lane >> 4;
  const int sx = l15 & 7;
  const int wm = wave & 1, wn = wave >> 1;
  const int bm = blockIdx.y, bn = blockIdx.x;

  f32x4 acc[4][2] = {};

  for (int k0 = 0; k0 < K; k0 += 64) {
    __syncthreads();
#pragma unroll
    for (int s = 0; s < 4; ++s) {
      int c = tid + s * 256;
      int row = c >> 3, cc = c & 7;
      int kc = (cc ^ (row & 7)) * 8;
      load_lds16(A + (size_t)(bm * 128 + row) * K + k0 + kc, As + c * 8);
    }
#pragma unroll
    for (int s = 0; s < 2; ++s) {
      int c = tid + s * 256;
      int row = c >> 3, cc = c & 7;
      int kc = (cc ^ (row & 7)) * 8;
      load_lds16(Bt + (size_t)(bn * 64 + row) * K + k0 + kc, Bs + c * 8);
    }
    __syncthreads();
#pragma unroll
    for (int kk = 0; kk < 2; ++kk) {
      s16x8 af[4], bfr[2];
#pragma unroll
      for (int i = 0; i < 4; ++i)
        af[i] = *(const s16x8*)(As + (wm * 64 + i * 16 + l15) * 64 + ((quad + 4 * kk) ^ sx) * 8);
#pragma unroll
      for (int j = 0; j < 2; ++j)
        bfr[j] = *(const s16x8*)(Bs + (wn * 32 + j * 16 + l15) * 64 + ((quad + 4 * kk) ^ sx) * 8);
#pragma unroll
      for (int i = 0; i < 4; ++i)
#pragma unroll
        for (int j = 0; j < 2; ++j)
          acc[i][j] = __builtin_amdgcn_mfma_f32_16x16x32_bf16(af[i], bfr[j], acc[i][j], 0, 0, 0);
    }
  }

  const int row0 = bm * 128 + wm * 64 + quad * 4;
  const int col0 = bn * 64 + wn * 32 + l15;
#pragma unroll
  for (int i = 0; i < 4; ++i)
#pragma unroll
    for (int j = 0; j < 2; ++j)
#pragma unroll
      for (int r = 0; r < 4; ++r)
        C[(size_t)(row0 + i * 16 + r) * N + (col0 + j * 16)] = acc[i][j][r];
}

// ---------------- flash attention v6: balanced work items + split-j ----------------
// 256 thr / 4 waves / 64 q-rows per item. Block p: col=(p&255)&7, bh=(p&255)>>3,
// a=p>>8; item = LUT[col*6+a] = (t, jbeg, jend). Unsplit (t<16) writes Y;
// split halves write unnormalized O^T + (m,l) partials, combined by attn_combine.
__global__ __launch_bounds__(256) void attn_kernel(const unsigned short* __restrict__ qkv,
                                                   const unsigned short* __restrict__ Vt,
                                                   unsigned short* __restrict__ Y,
                                                   float* __restrict__ PO,
                                                   float* __restrict__ PM,
                                                   float* __restrict__ PL) {
  __shared__ unsigned short Qs[64 * 64];  // Q tile, then wave-private P strips
  __shared__ unsigned short Ks[64 * 64];
  __shared__ unsigned short Vs[64 * 64];
  const int tid = threadIdx.x;
  const int wave = tid >> 6, lane = tid & 63;
  const int l15 = lane & 15, quad = lane >> 4;
  const int sx = l15 & 7, sx2 = sx << 1;

  const int p = blockIdx.x;
  const int c_ = p & 255, a_ = p >> 8;
  const int col = c_ & 7, bh = c_ >> 3;
  const int li = col * 6 + a_;
  const int t = LUT_T[li], jbeg = LUT_JB[li], jend = LUT_JE[li];
  const int q0 = t * 64;
  const int b = bh >> 4, h = bh & 15;
  const size_t base = (size_t)b * 2048 * 3072 + h * 64;
  const size_t vbase = (size_t)bh * 64 * 2048;

  // stage Q tile 64x64 (swizzled): 512 chunks, 2/thread
#pragma unroll
  for (int s = 0; s < 2; ++s) {
    int cid = tid + s * 256;
    int row = cid >> 3, cc = cid & 7;
    int kc = (cc ^ (row & 7)) * 8;
    load_lds16(qkv + base + (size_t)(q0 + row) * 3072 + kc, Qs + cid * 8);
  }
  __syncthreads();
  s16x8 qf[2];
  qf[0] = *(const s16x8*)(Qs + (wave * 16 + l15) * 64 + ((quad    ) ^ sx) * 8);
  qf[1] = *(const s16x8*)(Qs + (wave * 16 + l15) * 64 + ((quad + 4) ^ sx) * 8);

  f32x4 o[4] = {};
  float m_i = -1e30f, l_i = 0.f;
  const float kScale = 0.125f * 1.44269504f;  // 1/sqrt(64) * log2(e)
  const int qrow_w0 = q0 + wave * 16;
  const int qrow = qrow_w0 + l15;
  unsigned short* Pw = Qs + wave * 16 * 64;   // wave-private P strip

  for (int jt = jbeg; jt < jend; ++jt) {
    const int j0 = jt * 64;
    __syncthreads();
#pragma unroll
    for (int s = 0; s < 2; ++s) {
      int c = tid + s * 256;
      int row = c >> 3, cc = c & 7;
      int kc = (cc ^ (row & 7)) * 8;
      load_lds16(qkv + base + (size_t)(j0 + row) * 3072 + 1024 + kc, Ks + c * 8);
      load_lds16(Vt + vbase + (size_t)row * 2048 + j0 + kc, Vs + c * 8);
    }
    __syncthreads();

    // S^T = K·Q^T
    f32x4 s[4];
#pragma unroll
    for (int nt = 0; nt < 4; ++nt) {
      const int kr = nt * 16 + l15;
      s16x8 kf0 = *(const s16x8*)(Ks + kr * 64 + ((quad    ) ^ sx) * 8);
      s16x8 kf1 = *(const s16x8*)(Ks + kr * 64 + ((quad + 4) ^ sx) * 8);
      f32x4 z = {};
      z = __builtin_amdgcn_mfma_f32_16x16x32_bf16(kf0, qf[0], z, 0, 0, 0);
      z = __builtin_amdgcn_mfma_f32_16x16x32_bf16(kf1, qf[1], z, 0, 0, 0);
      s[nt] = z;
    }

    // causal mask: only the diagonal j-block needs it
    if (j0 + 63 > qrow_w0) {
#pragma unroll
      for (int nt = 0; nt < 4; ++nt) {
        int key0 = j0 + nt * 16 + quad * 4;
#pragma unroll
        for (int r = 0; r < 4; ++r)
          if (key0 + r > qrow) s[nt][r] = -3e38f;
      }
    }

    // online softmax: per-lane q-row; reduce over quads (xor 16, 32)
    float tmax = s[0][0];
#pragma unroll
    for (int nt = 0; nt < 4; ++nt)
#pragma unroll
      for (int r = 0; r < 4; ++r)
        tmax = fmaxf(tmax, s[nt][r]);
    tmax = fmaxf(tmax, __shfl_xor(tmax, 16, 64));
    tmax = fmaxf(tmax, __shfl_xor(tmax, 32, 64));
    float mn = fmaxf(m_i, tmax);
    float alpha = __builtin_amdgcn_exp2f((m_i - mn) * kScale);
    m_i = mn;
    const float mk = mn * kScale;
    float rsum = 0.f;
#pragma unroll
    for (int nt = 0; nt < 4; ++nt)
#pragma unroll
      for (int r = 0; r < 4; ++r) {
        float pv = __builtin_amdgcn_exp2f(__builtin_fmaf(s[nt][r], kScale, -mk));
        s[nt][r] = pv;
        rsum += pv;
      }
    rsum += __shfl_xor(rsum, 16, 64);
    rsum += __shfl_xor(rsum, 32, 64);
    l_i = l_i * alpha + rsum;
#pragma unroll
    for (int dt = 0; dt < 4; ++dt)
#pragma unroll
      for (int r = 0; r < 4; ++r)
        o[dt][r] *= alpha;

    // P row l15 -> wave-private strip (b64 writes, 8B-chunk XOR swizzle)
#pragma unroll
    for (int nt = 0; nt < 4; ++nt) {
      u32x2 pk;
      pk.x = pack_bf2(s[nt][0], s[nt][1]);
      pk.y = pack_bf2(s[nt][2], s[nt][3]);
      int phys = (nt * 4 + quad) ^ sx2;
      *(u32x2*)(Pw + l15 * 64 + phys * 4) = pk;
    }

    s16x8 pf[2];
    pf[0] = *(const s16x8*)(Pw + l15 * 64 + (((quad * 2)    ) ^ sx2) * 4);
    pf[1] = *(const s16x8*)(Pw + l15 * 64 + (((quad * 2) + 8) ^ sx2) * 4);

    // O^T += V^T · P^T
#pragma unroll
    for (int dt = 0; dt < 4; ++dt) {
      const int vr = dt * 16 + l15;
      s16x8 vf0 = *(const s16x8*)(Vs + vr * 64 + ((quad    ) ^ sx) * 8);
      s16x8 vf1 = *(const s16x8*)(Vs + vr * 64 + ((quad + 4) ^ sx) * 8);
      o[dt] = __builtin_amdgcn_mfma_f32_16x16x32_bf16(vf0, pf[0], o[dt], 0, 0, 0);
      o[dt] = __builtin_amdgcn_mfma_f32_16x16x32_bf16(vf1, pf[1], o[dt], 0, 0, 0);
    }
  }

  if (t < 16) {
    const float inv = 1.0f / l_i;
    const size_t yoff = (size_t)(b * 2048 + qrow) * 1024 + h * 64 + quad * 4;
#pragma unroll
    for (int dt = 0; dt < 4; ++dt) {
      u16x4 pk;
#pragma unroll
      for (int r = 0; r < 4; ++r) pk[r] = f2bf(o[dt][r] * inv);
      *(u16x4*)(Y + yoff + dt * 16) = pk;
    }
  } else {
    const int half = (jbeg == 0) ? 0 : 1;
    const int idx = (bh * 16 + (t - 16)) * 2 + half;
    const int qlocal = wave * 16 + l15;
    float* POb = PO + (size_t)idx * 4096 + qlocal * 64;
#pragma unroll
    for (int dt = 0; dt < 4; ++dt)
      *(f32x4*)(POb + dt * 16 + quad * 4) = o[dt];
    if (quad == 0) {
      PM[idx * 64 + qlocal] = m_i;
      PL[idx * 64 + qlocal] = l_i;
    }
  }
}

// ---------------- combine partials for split items ----------------
// rows = 32 bh x 16 t' x 64 q = 32768; block = 4 rows x 64 d; grid 512 x 16 iters.
__global__ __launch_bounds__(256) void attn_combine(const float* __restrict__ PO,
                                                    const float* __restrict__ PM,
                                                    const float* __restrict__ PL,
                                                    unsigned short* __restrict__ Y) {
  const int tid = threadIdx.x;
  const int d = tid & 63;
  const float kScale = 0.125f * 1.44269504f;
  for (int it = 0; it < 16; ++it) {
    int R = blockIdx.x * 64 + it * 4 + (tid >> 6);
    int bh = R >> 10, rem = R & 1023, tp = rem >> 6, q = rem & 63;
    int i2 = (bh * 16 + tp) * 2;
    float m1 = PM[i2 * 64 + q], l1 = PL[i2 * 64 + q];
    float m2 = PM[(i2 + 1) * 64 + q], l2 = PL[(i2 + 1) * 64 + q];
    float m = fmaxf(m1, m2);
    float a1 = __builtin_amdgcn_exp2f((m1 - m) * kScale);
    float a2 = __builtin_amdgcn_exp2f((m2 - m) * kScale);
    size_t o1 = (size_t)i2 * 4096 + q * 64 + d;
    float v = (PO[o1] * a1 + PO[o1 + 4096] * a2) / (l1 * a1 + l2 * a2);
    int b = bh >> 4, h = bh & 15, qrow = (tp + 16) * 64 + q;
    Y[(size_t)(b * 2048 + qrow) * 1024 + h * 64 + d] = f2bf(v);
  }
}

extern "C" void kernel_launch(void* const* d_in, const int* in_sizes, int n_in,
                              void* d_out, int out_size, void* d_ws, size_t ws_size,
                              hipStream_t stream) {
  const float* x      = (const float*)d_in[0];  // [2,2048,1024]
  const float* w_qkv  = (const float*)d_in[1];  // [1024,3072]
  const float* w_proj = (const float*)d_in[2];  // [1024,1024]
  char* ws = (char*)d_ws;
  unsigned short* xb     = (unsigned short*)(ws);                      //  8 MiB
  unsigned short* wqkvT  = (unsigned short*)(ws + (size_t)(8  << 20)); //  6 MiB
  unsigned short* wprojT = (unsigned short*)(ws + (size_t)(14 << 20)); //  2 MiB
  unsigned short* qkv    = (unsigned short*)(ws + (size_t)(16 << 20)); // 24 MiB
  unsigned short* y      = (unsigned short*)(ws + (size_t)(40 << 20)); //  8 MiB
  unsigned short* Vt     = (unsigned short*)(ws + (size_t)(48 << 20)); //  8 MiB
  float*          PO     = (float*)(ws + (size_t)(56 << 20));          // 16 MiB [1024][2][64][64]
  float*          PM     = (float*)(ws + (size_t)(73 << 20));          // 0.5 MiB
  float*          PL     = (float*)(ws + (size_t)(74 << 20));          // 0.5 MiB

  prep_kernel<<<8192, 256, 0, stream>>>(x, w_qkv, w_proj, xb, wqkvT, wprojT);
  gemm_qkv<<<dim3(24, 32), 256, 0, stream>>>(xb, wqkvT, qkv, 4096, 3072, 1024);
  transpose_v<<<dim3(32, 32), 256, 0, stream>>>(qkv, Vt);
  attn_kernel<<<1536, 256, 0, stream>>>(qkv, Vt, y, PO, PM, PL);
  attn_combine<<<512, 256, 0, stream>>>(PO, PM, PL, y);
  gemm_proj<<<dim3(16, 32), 256, 0, stream>>>(y, wprojT, (float*)d_out, 4096, 1024, 1024);
}

// Round 10
// 187.504 us; speedup vs baseline: 1.0045x; 1.0045x over previous
//
#include <hip/hip_runtime.h>

#define AS1 __attribute__((address_space(1)))
#define AS3 __attribute__((address_space(3)))

using f32x4 = __attribute__((ext_vector_type(4))) float;
using s16x8 = __attribute__((ext_vector_type(8))) short;
using u16x4 = __attribute__((ext_vector_type(4))) unsigned short;
using u32x2 = __attribute__((ext_vector_type(2))) unsigned int;

__device__ __forceinline__ unsigned short f2bf(float f) {
  union { float f; unsigned u; } v; v.f = f;
  unsigned u = v.u;
  return (unsigned short)((u + 0x7FFFu + ((u >> 16) & 1u)) >> 16);  // RNE
}

__device__ __forceinline__ unsigned pack_bf2(float a, float b) {  // trunc; P in [0,1]
  union { float f; unsigned u; } x, y; x.f = a; y.f = b;
  return (x.u >> 16) | (y.u & 0xFFFF0000u);
}

__device__ __forceinline__ void load_lds16(const void* g, void* l) {
  __builtin_amdgcn_global_load_lds((const AS1 void*)g, (AS3 void*)l, 16, 0, 0);
}

// ---------------- fused prep: cast x + transpose both weights ----------------
__global__ __launch_bounds__(256) void prep_kernel(const float* __restrict__ x,
                                                   const float* __restrict__ w_qkv,
                                                   const float* __restrict__ w_proj,
                                                   unsigned short* __restrict__ xb,
                                                   unsigned short* __restrict__ wqkvT,
                                                   unsigned short* __restrict__ wprojT) {
  __shared__ float tile[32][33];
  const int bid = blockIdx.x, tid = threadIdx.x;
  if (bid < 4096) {
    int i = bid * 256 + tid;
    float4 v = ((const float4*)x)[i];
    u16x4 o;
    o.x = f2bf(v.x); o.y = f2bf(v.y); o.z = f2bf(v.z); o.w = f2bf(v.w);
    ((u16x4*)xb)[i] = o;
    return;
  }
  const float* in;
  unsigned short* out;
  int bx, by, R, C;
  if (bid < 7168) {
    int t = bid - 4096;
    bx = t % 96; by = t / 96; R = 1024; C = 3072;
    in = w_qkv; out = wqkvT;
  } else {
    int t = bid - 7168;
    bx = t % 32; by = t / 32; R = 1024; C = 1024;
    in = w_proj; out = wprojT;
  }
  const int tx = tid & 31, ty = tid >> 5;
  int xcol = bx * 32 + tx;
  int y0 = by * 32;
  for (int j = ty; j < 32; j += 8)
    tile[j][tx] = in[(size_t)(y0 + j) * C + xcol];
  __syncthreads();
  int x2 = by * 32 + tx;
  int y2 = bx * 32;
  for (int j = ty; j < 32; j += 8)
    out[(size_t)(y2 + j) * R + x2] = f2bf(tile[tx][j]);
}

// ---------------- V transpose: qkv V block [s][d] -> Vt[b][h][d][s] ----------------
__global__ __launch_bounds__(256) void transpose_v(const unsigned short* __restrict__ qkv,
                                                   unsigned short* __restrict__ Vt) {
  __shared__ unsigned short tile[64][65];
  const int tid = threadIdx.x;
  const int bh = blockIdx.y, b = bh >> 4, h = bh & 15;
  const int s0 = blockIdx.x * 64;
#pragma unroll
  for (int it = 0; it < 2; ++it) {
    int c = tid + it * 256;
    int row = c >> 3, cc = c & 7;
    s16x8 v = *(const s16x8*)(qkv + (size_t)(b * 2048 + s0 + row) * 3072 + 2048 + h * 64 + cc * 8);
#pragma unroll
    for (int j = 0; j < 8; ++j) tile[row][cc * 8 + j] = (unsigned short)v[j];
  }
  __syncthreads();
#pragma unroll
  for (int it = 0; it < 2; ++it) {
    int c = tid + it * 256;
    int d = c >> 3, sc = c & 7;
    s16x8 o;
#pragma unroll
    for (int j = 0; j < 8; ++j) o[j] = (short)tile[sc * 8 + j][d];
    *(s16x8*)(Vt + (size_t)bh * 64 * 2048 + (size_t)d * 2048 + s0 + sc * 8) = o;
  }
}

// ---------------- QKV GEMM: 64Mx128N tile, BK=64, swizzled; 1536 blocks (6/CU) ----------------
// Small tiles -> more independent blocks per CU to hide the per-iter barrier drain.
__global__ __launch_bounds__(256) void gemm_qkv(const unsigned short* __restrict__ A,
                                                const unsigned short* __restrict__ Bt,
                                                unsigned short* __restrict__ C,
                                                int M, int N, int K) {
  __shared__ unsigned short As[64 * 64];
  __shared__ unsigned short Bs[128 * 64];
  const int tid = threadIdx.x;
  const int wave = tid >> 6, lane = tid & 63;
  const int l15 = lane & 15, quad = lane >> 4;
  const int sx = l15 & 7;
  const int wm = wave & 1, wn = wave >> 1;   // wave-tile 32M x 64N
  const int bm = blockIdx.y, bn = blockIdx.x;

  f32x4 acc[2][4] = {};

  for (int k0 = 0; k0 < K; k0 += 64) {
    __syncthreads();
    {  // A: 512 chunks, 2/thread
      int c = tid;
#pragma unroll
      for (int s = 0; s < 2; ++s, c += 256) {
        int row = c >> 3, cc = c & 7;
        int kc = (cc ^ (row & 7)) * 8;
        load_lds16(A + (size_t)(bm * 64 + row) * K + k0 + kc, As + c * 8);
      }
    }
    {  // B: 1024 chunks, 4/thread
      int c = tid;
#pragma unroll
      for (int s = 0; s < 4; ++s, c += 256) {
        int row = c >> 3, cc = c & 7;
        int kc = (cc ^ (row & 7)) * 8;
        load_lds16(Bt + (size_t)(bn * 128 + row) * K + k0 + kc, Bs + c * 8);
      }
    }
    __syncthreads();
#pragma unroll
    for (int kk = 0; kk < 2; ++kk) {
      s16x8 af[2], bfr[4];
#pragma unroll
      for (int i = 0; i < 2; ++i)
        af[i] = *(const s16x8*)(As + (wm * 32 + i * 16 + l15) * 64 + ((quad + 4 * kk) ^ sx) * 8);
#pragma unroll
      for (int j = 0; j < 4; ++j)
        bfr[j] = *(const s16x8*)(Bs + (wn * 64 + j * 16 + l15) * 64 + ((quad + 4 * kk) ^ sx) * 8);
#pragma unroll
      for (int i = 0; i < 2; ++i)
#pragma unroll
        for (int j = 0; j < 4; ++j)
          acc[i][j] = __builtin_amdgcn_mfma_f32_16x16x32_bf16(af[i], bfr[j], acc[i][j], 0, 0, 0);
    }
  }

  const int row0 = bm * 64 + wm * 32 + quad * 4;
  const int col0 = bn * 128 + wn * 64 + l15;
#pragma unroll
  for (int i = 0; i < 2; ++i)
#pragma unroll
    for (int j = 0; j < 4; ++j)
#pragma unroll
      for (int r = 0; r < 4; ++r)
        C[(size_t)(row0 + i * 16 + r) * N + (col0 + j * 16)] = f2bf(acc[i][j][r]);
}

// ---------------- proj GEMM: 64x64 tile, BK=64, swizzled; 1024 blocks (4/CU); f32 out ----------------
__global__ __launch_bounds__(256) void gemm_proj(const unsigned short* __restrict__ A,
                                                 const unsigned short* __restrict__ Bt,
                                                 float* __restrict__ C,
                                                 int M, int N, int K) {
  __shared__ unsigned short As[64 * 64];
  __shared__ unsigned short Bs[64 * 64];
  const int tid = threadIdx.x;
  const int wave = tid >> 6, lane = tid & 63;
  const int l15 = lane & 15, quad = lane >> 4;
  const int sx = l15 & 7;
  const int wm = wave & 1, wn = wave >> 1;   // wave-tile 32M x 32N
  const int bm = blockIdx.y, bn = blockIdx.x;

  f32x4 acc[2][2] = {};

  for (int k0 = 0; k0 < K; k0 += 64) {
    __syncthreads();
    {
      int c = tid;
#pragma unroll
      for (int s = 0; s < 2; ++s, c += 256) {
        int row = c >> 3, cc = c & 7;
        int kc = (cc ^ (row & 7)) * 8;
        load_lds16(A + (size_t)(bm * 64 + row) * K + k0 + kc, As + c * 8);
        load_lds16(Bt + (size_t)(bn * 64 + row) * K + k0 + kc, Bs + c * 8);
      }
    }
    __syncthreads();
#pragma unroll
    for (int kk = 0; kk < 2; ++kk) {
      s16x8 af[2], bfr[2];
#pragma unroll
      for (int i = 0; i < 2; ++i) {
        af[i]  = *(const s16x8*)(As + (wm * 32 + i * 16 + l15) * 64 + ((quad + 4 * kk) ^ sx) * 8);
        bfr[i] = *(const s16x8*)(Bs + (wn * 32 + i * 16 + l15) * 64 + ((quad + 4 * kk) ^ sx) * 8);
      }
#pragma unroll
      for (int i = 0; i < 2; ++i)
#pragma unroll
        for (int j = 0; j < 2; ++j)
          acc[i][j] = __builtin_amdgcn_mfma_f32_16x16x32_bf16(af[i], bfr[j], acc[i][j], 0, 0, 0);
    }
  }

  const int row0 = bm * 64 + wm * 32 + quad * 4;
  const int col0 = bn * 64 + wn * 32 + l15;
#pragma unroll
  for (int i = 0; i < 2; ++i)
#pragma unroll
    for (int j = 0; j < 2; ++j)
#pragma unroll
      for (int r = 0; r < 4; ++r)
        C[(size_t)(row0 + i * 16 + r) * N + (col0 + j * 16)] = acc[i][j][r];
}

// ---------------- flash attention (v5 verified 50.6 us): S^T formulation ----------------
// S^T = K·Q^T; lane owns one q-row (l15) -> softmax reduce = in-reg + 2 shfl;
// P via 4 ds_write_b64 + 2 b128 reads; O^T = V^T·P^T. 128 q-rows, 8 waves, grid 512
// with CU-pairing (lq, 15-lq).
__global__ __launch_bounds__(512) void attn_kernel(const unsigned short* __restrict__ qkv,
                                                   const unsigned short* __restrict__ Vt,
                                                   unsigned short* __restrict__ Y) {
  __shared__ unsigned short Qs[128 * 64];  // Q tile, then wave-private P strips
  __shared__ unsigned short Ks[64 * 64];
  __shared__ unsigned short Vs[64 * 64];   // Vt tile: rows = d, cols = keys
  const int tid = threadIdx.x;
  const int wave = tid >> 6, lane = tid & 63;
  const int l15 = lane & 15, quad = lane >> 4;
  const int sx = l15 & 7, sx2 = sx << 1;

  const int p = blockIdx.x;
  const int r_ = p >> 8, c_ = p & 255;
  const int m_ = c_ & 15, g_ = c_ >> 4;
  const int bh = g_ + 16 * r_;
  const int lq = r_ ? (15 - m_) : m_;
  const int q0 = lq * 128;
  const int b = bh >> 4, h = bh & 15;
  const size_t base = (size_t)b * 2048 * 3072 + h * 64;
  const size_t vbase = (size_t)bh * 64 * 2048;

#pragma unroll
  for (int s = 0; s < 2; ++s) {
    int cid = tid + s * 512;
    int row = cid >> 3, cc = cid & 7;
    int kc = (cc ^ (row & 7)) * 8;
    load_lds16(qkv + base + (size_t)(q0 + row) * 3072 + kc, Qs + cid * 8);
  }
  __syncthreads();
  s16x8 qf[2];
  qf[0] = *(const s16x8*)(Qs + (wave * 16 + l15) * 64 + ((quad    ) ^ sx) * 8);
  qf[1] = *(const s16x8*)(Qs + (wave * 16 + l15) * 64 + ((quad + 4) ^ sx) * 8);

  f32x4 o[4] = {};
  float m_i = -1e30f, l_i = 0.f;
  const float kScale = 0.125f * 1.44269504f;  // 1/sqrt(64) * log2(e)
  const int qrow_w0 = q0 + wave * 16;
  const int qrow = qrow_w0 + l15;
  unsigned short* Pw = Qs + wave * 16 * 64;   // wave-private P strip

  for (int j0 = 0; j0 <= q0 + 64; j0 += 64) {
    __syncthreads();
    {
      int row = tid >> 3, cc = tid & 7;
      int kc = (cc ^ (row & 7)) * 8;
      load_lds16(qkv + base + (size_t)(j0 + row) * 3072 + 1024 + kc, Ks + tid * 8);
      load_lds16(Vt + vbase + (size_t)row * 2048 + j0 + kc, Vs + tid * 8);
    }
    __syncthreads();

    if (j0 <= qrow_w0 + 15) {
      f32x4 s[4];
#pragma unroll
      for (int nt = 0; nt < 4; ++nt) {
        const int kr = nt * 16 + l15;
        s16x8 kf0 = *(const s16x8*)(Ks + kr * 64 + ((quad    ) ^ sx) * 8);
        s16x8 kf1 = *(const s16x8*)(Ks + kr * 64 + ((quad + 4) ^ sx) * 8);
        f32x4 z = {};
        z = __builtin_amdgcn_mfma_f32_16x16x32_bf16(kf0, qf[0], z, 0, 0, 0);
        z = __builtin_amdgcn_mfma_f32_16x16x32_bf16(kf1, qf[1], z, 0, 0, 0);
        s[nt] = z;
      }

      if (j0 + 63 > qrow_w0) {
#pragma unroll
        for (int nt = 0; nt < 4; ++nt) {
          int key0 = j0 + nt * 16 + quad * 4;
#pragma unroll
          for (int r = 0; r < 4; ++r)
            if (key0 + r > qrow) s[nt][r] = -3e38f;
        }
      }

      float tmax = s[0][0];
#pragma unroll
      for (int nt = 0; nt < 4; ++nt)
#pragma unroll
        for (int r = 0; r < 4; ++r)
          tmax = fmaxf(tmax, s[nt][r]);
      tmax = fmaxf(tmax, __shfl_xor(tmax, 16, 64));
      tmax = fmaxf(tmax, __shfl_xor(tmax, 32, 64));
      float mn = fmaxf(m_i, tmax);
      float alpha = __builtin_amdgcn_exp2f((m_i - mn) * kScale);
      m_i = mn;
      const float mk = mn * kScale;
      float rsum = 0.f;
#pragma unroll
      for (int nt = 0; nt < 4; ++nt)
#pragma unroll
        for (int r = 0; r < 4; ++r) {
          float pv = __builtin_amdgcn_exp2f(__builtin_fmaf(s[nt][r], kScale, -mk));
          s[nt][r] = pv;
          rsum += pv;
        }
      rsum += __shfl_xor(rsum, 16, 64);
      rsum += __shfl_xor(rsum, 32, 64);
      l_i = l_i * alpha + rsum;
#pragma unroll
      for (int dt = 0; dt < 4; ++dt)
#pragma unroll
        for (int r = 0; r < 4; ++r)
          o[dt][r] *= alpha;

#pragma unroll
      for (int nt = 0; nt < 4; ++nt) {
        u32x2 pk;
        pk.x = pack_bf2(s[nt][0], s[nt][1]);
        pk.y = pack_bf2(s[nt][2], s[nt][3]);
        int phys = (nt * 4 + quad) ^ sx2;
        *(u32x2*)(Pw + l15 * 64 + phys * 4) = pk;
      }

      s16x8 pf[2];
      pf[0] = *(const s16x8*)(Pw + l15 * 64 + (((quad * 2)    ) ^ sx2) * 4);
      pf[1] = *(const s16x8*)(Pw + l15 * 64 + (((quad * 2) + 8) ^ sx2) * 4);

#pragma unroll
      for (int dt = 0; dt < 4; ++dt) {
        const int vr = dt * 16 + l15;
        s16x8 vf0 = *(const s16x8*)(Vs + vr * 64 + ((quad    ) ^ sx) * 8);
        s16x8 vf1 = *(const s16x8*)(Vs + vr * 64 + ((quad + 4) ^ sx) * 8);
        o[dt] = __builtin_amdgcn_mfma_f32_16x16x32_bf16(vf0, pf[0], o[dt], 0, 0, 0);
        o[dt] = __builtin_amdgcn_mfma_f32_16x16x32_bf16(vf1, pf[1], o[dt], 0, 0, 0);
      }
    }
  }

  const float inv = 1.0f / l_i;
  const size_t yoff = (size_t)(b * 2048 + qrow) * 1024 + h * 64 + quad * 4;
#pragma unroll
  for (int dt = 0; dt < 4; ++dt) {
    u16x4 pk;
#pragma unroll
    for (int r = 0; r < 4; ++r) pk[r] = f2bf(o[dt][r] * inv);
    *(u16x4*)(Y + yoff + dt * 16) = pk;
  }
}

extern "C" void kernel_launch(void* const* d_in, const int* in_sizes, int n_in,
                              void* d_out, int out_size, void* d_ws, size_t ws_size,
                              hipStream_t stream) {
  const float* x      = (const float*)d_in[0];  // [2,2048,1024]
  const float* w_qkv  = (const float*)d_in[1];  // [1024,3072]
  const float* w_proj = (const float*)d_in[2];  // [1024,1024]
  char* ws = (char*)d_ws;
  unsigned short* xb     = (unsigned short*)(ws);                      //  8 MiB
  unsigned short* wqkvT  = (unsigned short*)(ws + (size_t)(8  << 20)); //  6 MiB
  unsigned short* wprojT = (unsigned short*)(ws + (size_t)(14 << 20)); //  2 MiB
  unsigned short* qkv    = (unsigned short*)(ws + (size_t)(16 << 20)); // 24 MiB
  unsigned short* y      = (unsigned short*)(ws + (size_t)(40 << 20)); //  8 MiB
  unsigned short* Vt     = (unsigned short*)(ws + (size_t)(48 << 20)); //  8 MiB

  prep_kernel<<<8192, 256, 0, stream>>>(x, w_qkv, w_proj, xb, wqkvT, wprojT);
  gemm_qkv<<<dim3(24, 64), 256, 0, stream>>>(xb, wqkvT, qkv, 4096, 3072, 1024);
  transpose_v<<<dim3(32, 32), 256, 0, stream>>>(qkv, Vt);
  attn_kernel<<<512, 512, 0, stream>>>(qkv, Vt, y);
  gemm_proj<<<dim3(16, 64), 256, 0, stream>>>(y, wprojT, (float*)d_out, 4096, 1024, 1024);
}

// Round 11
// 186.033 us; speedup vs baseline: 1.0124x; 1.0079x over previous
//
#include <hip/hip_runtime.h>

#define AS1 __attribute__((address_space(1)))
#define AS3 __attribute__((address_space(3)))

using f32x4 = __attribute__((ext_vector_type(4))) float;
using s16x8 = __attribute__((ext_vector_type(8))) short;
using u16x4 = __attribute__((ext_vector_type(4))) unsigned short;
using u32x2 = __attribute__((ext_vector_type(2))) unsigned int;

__device__ __forceinline__ unsigned short f2bf(float f) {
  union { float f; unsigned u; } v; v.f = f;
  unsigned u = v.u;
  return (unsigned short)((u + 0x7FFFu + ((u >> 16) & 1u)) >> 16);  // RNE
}

__device__ __forceinline__ unsigned pack_bf2(float a, float b) {  // trunc; P in [0,1]
  union { float f; unsigned u; } x, y; x.f = a; y.f = b;
  return (x.u >> 16) | (y.u & 0xFFFF0000u);
}

__device__ __forceinline__ void load_lds16(const void* g, void* l) {
  __builtin_amdgcn_global_load_lds((const AS1 void*)g, (AS3 void*)l, 16, 0, 0);
}

// ---------------- fused prep: cast x + transpose both weights ----------------
__global__ __launch_bounds__(256) void prep_kernel(const float* __restrict__ x,
                                                   const float* __restrict__ w_qkv,
                                                   const float* __restrict__ w_proj,
                                                   unsigned short* __restrict__ xb,
                                                   unsigned short* __restrict__ wqkvT,
                                                   unsigned short* __restrict__ wprojT) {
  __shared__ float tile[32][33];
  const int bid = blockIdx.x, tid = threadIdx.x;
  if (bid < 4096) {
    int i = bid * 256 + tid;
    float4 v = ((const float4*)x)[i];
    u16x4 o;
    o.x = f2bf(v.x); o.y = f2bf(v.y); o.z = f2bf(v.z); o.w = f2bf(v.w);
    ((u16x4*)xb)[i] = o;
    return;
  }
  const float* in;
  unsigned short* out;
  int bx, by, R, C;
  if (bid < 7168) {
    int t = bid - 4096;
    bx = t % 96; by = t / 96; R = 1024; C = 3072;
    in = w_qkv; out = wqkvT;
  } else {
    int t = bid - 7168;
    bx = t % 32; by = t / 32; R = 1024; C = 1024;
    in = w_proj; out = wprojT;
  }
  const int tx = tid & 31, ty = tid >> 5;
  int xcol = bx * 32 + tx;
  int y0 = by * 32;
  for (int j = ty; j < 32; j += 8)
    tile[j][tx] = in[(size_t)(y0 + j) * C + xcol];
  __syncthreads();
  int x2 = by * 32 + tx;
  int y2 = bx * 32;
  for (int j = ty; j < 32; j += 8)
    out[(size_t)(y2 + j) * R + x2] = f2bf(tile[tx][j]);
}

// ---------------- QK GEMM: qk[M,2048] = xb[M,K] * wqkT[2048,K]^T, bf16 out ----------------
// R8-verified 128x128 tile, BK=64, XOR-swizzled LDS; grid (16,32)=512 blocks.
__global__ __launch_bounds__(256) void gemm_qk(const unsigned short* __restrict__ A,
                                               const unsigned short* __restrict__ Bt,
                                               unsigned short* __restrict__ C,
                                               int M, int N, int K) {
  __shared__ unsigned short As[128 * 64];
  __shared__ unsigned short Bs[128 * 64];
  const int tid = threadIdx.x;
  const int wave = tid >> 6, lane = tid & 63;
  const int l15 = lane & 15, quad = lane >> 4;
  const int sx = l15 & 7;
  const int wm = wave & 1, wn = wave >> 1;
  const int bm = blockIdx.y, bn = blockIdx.x;

  f32x4 acc[4][4] = {};

  for (int k0 = 0; k0 < K; k0 += 64) {
    __syncthreads();
#pragma unroll
    for (int s = 0; s < 4; ++s) {
      int c = tid + s * 256;
      int row = c >> 3, cc = c & 7;
      int kc = (cc ^ (row & 7)) * 8;
      load_lds16(A + (size_t)(bm * 128 + row) * K + k0 + kc, As + c * 8);
      load_lds16(Bt + (size_t)(bn * 128 + row) * K + k0 + kc, Bs + c * 8);
    }
    __syncthreads();
#pragma unroll
    for (int kk = 0; kk < 2; ++kk) {
      s16x8 af[4], bfr[4];
#pragma unroll
      for (int i = 0; i < 4; ++i) {
        af[i]  = *(const s16x8*)(As + (wm * 64 + i * 16 + l15) * 64 + ((quad + 4 * kk) ^ sx) * 8);
        bfr[i] = *(const s16x8*)(Bs + (wn * 64 + i * 16 + l15) * 64 + ((quad + 4 * kk) ^ sx) * 8);
      }
#pragma unroll
      for (int i = 0; i < 4; ++i)
#pragma unroll
        for (int j = 0; j < 4; ++j)
          acc[i][j] = __builtin_amdgcn_mfma_f32_16x16x32_bf16(af[i], bfr[j], acc[i][j], 0, 0, 0);
    }
  }

  const int row0 = bm * 128 + wm * 64 + quad * 4;
  const int col0 = bn * 128 + wn * 64 + l15;
#pragma unroll
  for (int i = 0; i < 4; ++i)
#pragma unroll
    for (int j = 0; j < 4; ++j)
#pragma unroll
      for (int r = 0; r < 4; ++r)
        C[(size_t)(row0 + i * 16 + r) * N + (col0 + j * 16)] = f2bf(acc[i][j][r]);
}

// ---------------- Vt GEMM: Vt[1024, 4096] = wvT[1024,K] * xb[4096,K]^T ----------------
// Roles swapped vs qkv: M = (h,d), N = (b,s). C cols = s -> coalesced stores into
// Vt layout. 64Mx128N tile, grid (32,16)=512 blocks (2/CU). Replaces transpose_v.
__global__ __launch_bounds__(256) void gemm_vt(const unsigned short* __restrict__ A,
                                               const unsigned short* __restrict__ Bt,
                                               unsigned short* __restrict__ C,
                                               int M, int N, int K) {
  __shared__ unsigned short As[64 * 64];
  __shared__ unsigned short Bs[128 * 64];
  const int tid = threadIdx.x;
  const int wave = tid >> 6, lane = tid & 63;
  const int l15 = lane & 15, quad = lane >> 4;
  const int sx = l15 & 7;
  const int wm = wave & 1, wn = wave >> 1;   // wave-tile 32M x 64N
  const int bm = blockIdx.y, bn = blockIdx.x;

  f32x4 acc[2][4] = {};

  for (int k0 = 0; k0 < K; k0 += 64) {
    __syncthreads();
    {
      int c = tid;
#pragma unroll
      for (int s = 0; s < 2; ++s, c += 256) {
        int row = c >> 3, cc = c & 7;
        int kc = (cc ^ (row & 7)) * 8;
        load_lds16(A + (size_t)(bm * 64 + row) * K + k0 + kc, As + c * 8);
      }
    }
    {
      int c = tid;
#pragma unroll
      for (int s = 0; s < 4; ++s, c += 256) {
        int row = c >> 3, cc = c & 7;
        int kc = (cc ^ (row & 7)) * 8;
        load_lds16(Bt + (size_t)(bn * 128 + row) * K + k0 + kc, Bs + c * 8);
      }
    }
    __syncthreads();
#pragma unroll
    for (int kk = 0; kk < 2; ++kk) {
      s16x8 af[2], bfr[4];
#pragma unroll
      for (int i = 0; i < 2; ++i)
        af[i] = *(const s16x8*)(As + (wm * 32 + i * 16 + l15) * 64 + ((quad + 4 * kk) ^ sx) * 8);
#pragma unroll
      for (int j = 0; j < 4; ++j)
        bfr[j] = *(const s16x8*)(Bs + (wn * 64 + j * 16 + l15) * 64 + ((quad + 4 * kk) ^ sx) * 8);
#pragma unroll
      for (int i = 0; i < 2; ++i)
#pragma unroll
        for (int j = 0; j < 4; ++j)
          acc[i][j] = __builtin_amdgcn_mfma_f32_16x16x32_bf16(af[i], bfr[j], acc[i][j], 0, 0, 0);
    }
  }

  const int row0 = bm * 64 + wm * 32 + quad * 4;
  const int col0 = bn * 128 + wn * 64 + l15;
#pragma unroll
  for (int i = 0; i < 2; ++i)
#pragma unroll
    for (int j = 0; j < 4; ++j)
#pragma unroll
      for (int r = 0; r < 4; ++r)
        C[(size_t)(row0 + i * 16 + r) * N + (col0 + j * 16)] = f2bf(acc[i][j][r]);
}

// ---------------- proj GEMM (R8 config): 128Mx64N, BK=64, swizzled; f32 out ----------------
__global__ __launch_bounds__(256) void gemm_proj(const unsigned short* __restrict__ A,
                                                 const unsigned short* __restrict__ Bt,
                                                 float* __restrict__ C,
                                                 int M, int N, int K) {
  __shared__ unsigned short As[128 * 64];
  __shared__ unsigned short Bs[64 * 64];
  const int tid = threadIdx.x;
  const int wave = tid >> 6, lane = tid & 63;
  const int l15 = lane & 15, quad = lane >> 4;
  const int sx = l15 & 7;
  const int wm = wave & 1, wn = wave >> 1;
  const int bm = blockIdx.y, bn = blockIdx.x;

  f32x4 acc[4][2] = {};

  for (int k0 = 0; k0 < K; k0 += 64) {
    __syncthreads();
#pragma unroll
    for (int s = 0; s < 4; ++s) {
      int c = tid + s * 256;
      int row = c >> 3, cc = c & 7;
      int kc = (cc ^ (row & 7)) * 8;
      load_lds16(A + (size_t)(bm * 128 + row) * K + k0 + kc, As + c * 8);
    }
#pragma unroll
    for (int s = 0; s < 2; ++s) {
      int c = tid + s * 256;
      int row = c >> 3, cc = c & 7;
      int kc = (cc ^ (row & 7)) * 8;
      load_lds16(Bt + (size_t)(bn * 64 + row) * K + k0 + kc, Bs + c * 8);
    }
    __syncthreads();
#pragma unroll
    for (int kk = 0; kk < 2; ++kk) {
      s16x8 af[4], bfr[2];
#pragma unroll
      for (int i = 0; i < 4; ++i)
        af[i] = *(const s16x8*)(As + (wm * 64 + i * 16 + l15) * 64 + ((quad + 4 * kk) ^ sx) * 8);
#pragma unroll
      for (int j = 0; j < 2; ++j)
        bfr[j] = *(const s16x8*)(Bs + (wn * 32 + j * 16 + l15) * 64 + ((quad + 4 * kk) ^ sx) * 8);
#pragma unroll
      for (int i = 0; i < 4; ++i)
#pragma unroll
        for (int j = 0; j < 2; ++j)
          acc[i][j] = __builtin_amdgcn_mfma_f32_16x16x32_bf16(af[i], bfr[j], acc[i][j], 0, 0, 0);
    }
  }

  const int row0 = bm * 128 + wm * 64 + quad * 4;
  const int col0 = bn * 64 + wn * 32 + l15;
#pragma unroll
  for (int i = 0; i < 4; ++i)
#pragma unroll
    for (int j = 0; j < 2; ++j)
#pragma unroll
      for (int r = 0; r < 4; ++r)
        C[(size_t)(row0 + i * 16 + r) * N + (col0 + j * 16)] = acc[i][j][r];
}

// ---------------- flash attention v7: v5 + double-buffered K/V ----------------
// qk: [4096][2048] (q cols 0..1023, k cols 1024..2047); Vt: [1024][4096]
// (row = h*64+d, col = b*2048+s). One barrier per j-iter: next K/V tile's
// global_load_lds issues before compute of current tile; barrier drains after.
__global__ __launch_bounds__(512) void attn_kernel(const unsigned short* __restrict__ qk,
                                                   const unsigned short* __restrict__ Vt,
                                                   unsigned short* __restrict__ Y) {
  __shared__ unsigned short Qs[128 * 64];   // Q tile, then wave-private P strips
  __shared__ unsigned short Ks[2][64 * 64];
  __shared__ unsigned short Vs[2][64 * 64];
  const int tid = threadIdx.x;
  const int wave = tid >> 6, lane = tid & 63;
  const int l15 = lane & 15, quad = lane >> 4;
  const int sx = l15 & 7, sx2 = sx << 1;

  const int p = blockIdx.x;
  const int r_ = p >> 8, c_ = p & 255;
  const int m_ = c_ & 15, g_ = c_ >> 4;
  const int bh = g_ + 16 * r_;
  const int lq = r_ ? (15 - m_) : m_;
  const int q0 = lq * 128;
  const int b = bh >> 4, h = bh & 15;
  const size_t base = (size_t)b * 2048 * 2048 + h * 64;      // qk row stride 2048
  const size_t vtb = (size_t)(h * 64) * 4096 + b * 2048;     // Vt row stride 4096

  const int srow = tid >> 3, scc = tid & 7;
  const int skc = (scc ^ (srow & 7)) * 8;

  // stage Q (1024 chunks, 2/thread) + K/V tile 0
#pragma unroll
  for (int s = 0; s < 2; ++s) {
    int cid = tid + s * 512;
    int row = cid >> 3, cc = cid & 7;
    int kc = (cc ^ (row & 7)) * 8;
    load_lds16(qk + base + (size_t)(q0 + row) * 2048 + kc, Qs + cid * 8);
  }
  load_lds16(qk + base + (size_t)srow * 2048 + 1024 + skc, &Ks[0][0] + tid * 8);
  load_lds16(Vt + vtb + (size_t)srow * 4096 + skc, &Vs[0][0] + tid * 8);
  __syncthreads();

  s16x8 qf[2];
  qf[0] = *(const s16x8*)(Qs + (wave * 16 + l15) * 64 + ((quad    ) ^ sx) * 8);
  qf[1] = *(const s16x8*)(Qs + (wave * 16 + l15) * 64 + ((quad + 4) ^ sx) * 8);

  f32x4 o[4] = {};
  float m_i = -1e30f, l_i = 0.f;
  const float kScale = 0.125f * 1.44269504f;  // 1/sqrt(64) * log2(e)
  const int qrow_w0 = q0 + wave * 16;
  const int qrow = qrow_w0 + l15;
  unsigned short* Pw = Qs + wave * 16 * 64;   // wave-private P strip

  const int nIters = (q0 >> 6) + 2;
  for (int jt = 0; jt < nIters; ++jt) {
    const int j0 = jt << 6;
    const int cur = jt & 1;
    if (jt + 1 < nIters) {  // prefetch next tile into alt buffers (in flight during compute)
      const int jn = j0 + 64, nxt = cur ^ 1;
      load_lds16(qk + base + (size_t)(jn + srow) * 2048 + 1024 + skc, &Ks[nxt][0] + tid * 8);
      load_lds16(Vt + vtb + (size_t)srow * 4096 + jn + skc, &Vs[nxt][0] + tid * 8);
    }

    if (j0 <= qrow_w0 + 15) {
      const unsigned short* Ksb = &Ks[cur][0];
      const unsigned short* Vsb = &Vs[cur][0];

      f32x4 s[4];
#pragma unroll
      for (int nt = 0; nt < 4; ++nt) {
        const int kr = nt * 16 + l15;
        s16x8 kf0 = *(const s16x8*)(Ksb + kr * 64 + ((quad    ) ^ sx) * 8);
        s16x8 kf1 = *(const s16x8*)(Ksb + kr * 64 + ((quad + 4) ^ sx) * 8);
        f32x4 z = {};
        z = __builtin_amdgcn_mfma_f32_16x16x32_bf16(kf0, qf[0], z, 0, 0, 0);
        z = __builtin_amdgcn_mfma_f32_16x16x32_bf16(kf1, qf[1], z, 0, 0, 0);
        s[nt] = z;
      }

      if (j0 + 63 > qrow_w0) {
#pragma unroll
        for (int nt = 0; nt < 4; ++nt) {
          int key0 = j0 + nt * 16 + quad * 4;
#pragma unroll
          for (int r = 0; r < 4; ++r)
            if (key0 + r > qrow) s[nt][r] = -3e38f;
        }
      }

      float tmax = s[0][0];
#pragma unroll
      for (int nt = 0; nt < 4; ++nt)
#pragma unroll
        for (int r = 0; r < 4; ++r)
          tmax = fmaxf(tmax, s[nt][r]);
      tmax = fmaxf(tmax, __shfl_xor(tmax, 16, 64));
      tmax = fmaxf(tmax, __shfl_xor(tmax, 32, 64));
      float mn = fmaxf(m_i, tmax);
      float alpha = __builtin_amdgcn_exp2f((m_i - mn) * kScale);
      m_i = mn;
      const float mk = mn * kScale;
      float rsum = 0.f;
#pragma unroll
      for (int nt = 0; nt < 4; ++nt)
#pragma unroll
        for (int r = 0; r < 4; ++r) {
          float pv = __builtin_amdgcn_exp2f(__builtin_fmaf(s[nt][r], kScale, -mk));
          s[nt][r] = pv;
          rsum += pv;
        }
      rsum += __shfl_xor(rsum, 16, 64);
      rsum += __shfl_xor(rsum, 32, 64);
      l_i = l_i * alpha + rsum;
#pragma unroll
      for (int dt = 0; dt < 4; ++dt)
#pragma unroll
        for (int r = 0; r < 4; ++r)
          o[dt][r] *= alpha;

#pragma unroll
      for (int nt = 0; nt < 4; ++nt) {
        u32x2 pk;
        pk.x = pack_bf2(s[nt][0], s[nt][1]);
        pk.y = pack_bf2(s[nt][2], s[nt][3]);
        int phys = (nt * 4 + quad) ^ sx2;
        *(u32x2*)(Pw + l15 * 64 + phys * 4) = pk;
      }

      s16x8 pf[2];
      pf[0] = *(const s16x8*)(Pw + l15 * 64 + (((quad * 2)    ) ^ sx2) * 4);
      pf[1] = *(const s16x8*)(Pw + l15 * 64 + (((quad * 2) + 8) ^ sx2) * 4);

#pragma unroll
      for (int dt = 0; dt < 4; ++dt) {
        const int vr = dt * 16 + l15;
        s16x8 vf0 = *(const s16x8*)(Vsb + vr * 64 + ((quad    ) ^ sx) * 8);
        s16x8 vf1 = *(const s16x8*)(Vsb + vr * 64 + ((quad + 4) ^ sx) * 8);
        o[dt] = __builtin_amdgcn_mfma_f32_16x16x32_bf16(vf0, pf[0], o[dt], 0, 0, 0);
        o[dt] = __builtin_amdgcn_mfma_f32_16x16x32_bf16(vf1, pf[1], o[dt], 0, 0, 0);
      }
    }
    __syncthreads();  // drains prefetch; protects buf reuse at jt+1
  }

  const float inv = 1.0f / l_i;
  const size_t yoff = (size_t)(b * 2048 + qrow) * 1024 + h * 64 + quad * 4;
#pragma unroll
  for (int dt = 0; dt < 4; ++dt) {
    u16x4 pk;
#pragma unroll
    for (int r = 0; r < 4; ++r) pk[r] = f2bf(o[dt][r] * inv);
    *(u16x4*)(Y + yoff + dt * 16) = pk;
  }
}

extern "C" void kernel_launch(void* const* d_in, const int* in_sizes, int n_in,
                              void* d_out, int out_size, void* d_ws, size_t ws_size,
                              hipStream_t stream) {
  const float* x      = (const float*)d_in[0];  // [2,2048,1024]
  const float* w_qkv  = (const float*)d_in[1];  // [1024,3072]
  const float* w_proj = (const float*)d_in[2];  // [1024,1024]
  char* ws = (char*)d_ws;
  unsigned short* xb     = (unsigned short*)(ws);                      //  8 MiB
  unsigned short* wqkvT  = (unsigned short*)(ws + (size_t)(8  << 20)); //  6 MiB
  unsigned short* wprojT = (unsigned short*)(ws + (size_t)(14 << 20)); //  2 MiB
  unsigned short* qk     = (unsigned short*)(ws + (size_t)(16 << 20)); // 16 MiB [4096,2048]
  unsigned short* y      = (unsigned short*)(ws + (size_t)(40 << 20)); //  8 MiB
  unsigned short* Vt     = (unsigned short*)(ws + (size_t)(48 << 20)); //  8 MiB [1024,4096]

  prep_kernel<<<8192, 256, 0, stream>>>(x, w_qkv, w_proj, xb, wqkvT, wprojT);
  gemm_qk<<<dim3(16, 32), 256, 0, stream>>>(xb, wqkvT, qk, 4096, 2048, 1024);
  gemm_vt<<<dim3(32, 16), 256, 0, stream>>>(wqkvT + (size_t)2048 * 1024, xb, Vt, 1024, 4096, 1024);
  attn_kernel<<<512, 512, 0, stream>>>(qk, Vt, y);
  gemm_proj<<<dim3(16, 32), 256, 0, stream>>>(y, wprojT, (float*)d_out, 4096, 1024, 1024);
}